// Round 6
// baseline (287.047 us; speedup 1.0000x reference)
//
#include <hip/hip_runtime.h>
#include <math.h>

#define NODES 32768
#define NEDGE 524288
#define ETOT  (NEDGE + NODES)

// =================== CSR build (once per call) ===================

__global__ void hist_kernel(const int* __restrict__ dstv, int* __restrict__ cnt)
{
    int e = blockIdx.x * blockDim.x + threadIdx.x;
    if (e >= ETOT) return;
    int d = (e < NEDGE) ? dstv[e] : (e - NEDGE);
    atomicAdd(&cnt[d], 1);
}

// single block, 1024 threads, 32 elements each -> exclusive scan of 32768 counts
__global__ __launch_bounds__(1024) void scan_csr(const int* __restrict__ cnt,
                                                 int* __restrict__ row_ptr,
                                                 int* __restrict__ cursor)
{
    __shared__ int ssum[1024];
    const int t = threadIdx.x;
    const int base = t * 32;
    int local[32];
    int s = 0;
    #pragma unroll
    for (int i = 0; i < 32; ++i) { local[i] = cnt[base + i]; s += local[i]; }
    ssum[t] = s;
    __syncthreads();
    for (int off = 1; off < 1024; off <<= 1) {
        int x = ssum[t];
        int y = (t >= off) ? ssum[t - off] : 0;
        __syncthreads();
        ssum[t] = x + y;
        __syncthreads();
    }
    int run = ssum[t] - s;           // exclusive prefix
    #pragma unroll
    for (int i = 0; i < 32; ++i) {
        row_ptr[base + i] = run;
        cursor[base + i] = run;
        run += local[i];
    }
    if (t == 1023) row_ptr[NODES] = run;
}

__global__ void fill_csr(const int* __restrict__ srcv, const int* __restrict__ dstv,
                         int* __restrict__ cursor, int* __restrict__ col)
{
    int e = blockIdx.x * blockDim.x + threadIdx.x;
    if (e >= ETOT) return;
    int s, d;
    if (e < NEDGE) { s = srcv[e]; d = dstv[e]; } else { s = d = e - NEDGE; }
    int pos = atomicAdd(&cursor[d], 1);
    col[pos] = s;
}

// =================== h = x @ W, fused al_s/al_d reductions ===================
// grid: (NODES/128, H). block: 256 threads.
// thread (cg = tid&15, ng = tid>>4) owns 8 nodes x 4 cols of this head's slab.
// als/ald written PADDED at stride 4.
template<int K>
__global__ __launch_bounds__(256) void linear_al(
    const float* __restrict__ x, const float* __restrict__ W,   // W: [K][M] k-major
    const float* __restrict__ a_s, const float* __restrict__ a_d,
    float* __restrict__ h, float* __restrict__ als4, float* __restrict__ ald4,
    int H)
{
    constexpr int KT = 64;
    __shared__ float xs[128 * KT];   // slot: row*16 + (q ^ ((row>>3)&3)), q = k/4
    __shared__ float ws[KT * 64];    // [kk][c]
    const int tid = threadIdx.x;
    const int cg = tid & 15;
    const int ng = tid >> 4;
    const int head = blockIdx.y;
    const int n0 = blockIdx.x * 128;
    const int M = H << 6;

    float acc[8][4];
    #pragma unroll
    for (int r = 0; r < 8; ++r)
        #pragma unroll
        for (int j = 0; j < 4; ++j) acc[r][j] = 0.f;

    for (int k0 = 0; k0 < K; k0 += KT) {
        #pragma unroll
        for (int it = 0; it < 8; ++it) {
            int u = tid + it * 256;
            int row = u >> 4, q = u & 15;
            float4 v = *reinterpret_cast<const float4*>(
                &x[(size_t)(n0 + row) * K + k0 + q * 4]);
            int slot = row * 16 + (q ^ ((row >> 3) & 3));
            *reinterpret_cast<float4*>(&xs[slot * 4]) = v;
        }
        #pragma unroll
        for (int it = 0; it < 4; ++it) {
            int u = tid + it * 256;
            int kk = u >> 4, cq = u & 15;
            float4 v = *reinterpret_cast<const float4*>(
                &W[(size_t)(k0 + kk) * M + head * 64 + cq * 4]);
            *reinterpret_cast<float4*>(&ws[kk * 64 + cq * 4]) = v;
        }
        __syncthreads();

        #pragma unroll
        for (int q = 0; q < 16; ++q) {
            float4 wv[4];
            #pragma unroll
            for (int i = 0; i < 4; ++i)
                wv[i] = *reinterpret_cast<const float4*>(&ws[(q * 4 + i) * 64 + cg * 4]);
            #pragma unroll
            for (int r = 0; r < 8; ++r) {
                const int row = ng * 8 + r;
                const int slot = row * 16 + (q ^ ((row >> 3) & 3));
                float4 xv = *reinterpret_cast<const float4*>(&xs[slot * 4]);
                acc[r][0] = fmaf(xv.x, wv[0].x, fmaf(xv.y, wv[1].x, fmaf(xv.z, wv[2].x, fmaf(xv.w, wv[3].x, acc[r][0]))));
                acc[r][1] = fmaf(xv.x, wv[0].y, fmaf(xv.y, wv[1].y, fmaf(xv.z, wv[2].y, fmaf(xv.w, wv[3].y, acc[r][1]))));
                acc[r][2] = fmaf(xv.x, wv[0].z, fmaf(xv.y, wv[1].z, fmaf(xv.z, wv[2].z, fmaf(xv.w, wv[3].z, acc[r][2]))));
                acc[r][3] = fmaf(xv.x, wv[0].w, fmaf(xv.y, wv[1].w, fmaf(xv.z, wv[2].w, fmaf(xv.w, wv[3].w, acc[r][3]))));
            }
        }
        __syncthreads();
    }

    const int c0 = head * 64 + cg * 4;
    const float* asp = a_s + c0;
    const float* adp = a_d + c0;
    const float s0 = asp[0], s1 = asp[1], s2 = asp[2], s3 = asp[3];
    const float d0 = adp[0], d1 = adp[1], d2 = adp[2], d3 = adp[3];

    #pragma unroll
    for (int r = 0; r < 8; ++r) {
        const int n = n0 + ng * 8 + r;
        float4 hv;
        hv.x = acc[r][0]; hv.y = acc[r][1]; hv.z = acc[r][2]; hv.w = acc[r][3];
        *reinterpret_cast<float4*>(&h[(size_t)n * M + c0]) = hv;
        float ps = acc[r][0] * s0 + acc[r][1] * s1 + acc[r][2] * s2 + acc[r][3] * s3;
        float pd = acc[r][0] * d0 + acc[r][1] * d1 + acc[r][2] * d2 + acc[r][3] * d3;
        #pragma unroll
        for (int off = 1; off < 16; off <<= 1) {
            ps += __shfl_xor(ps, off, 64);
            pd += __shfl_xor(pd, off, 64);
        }
        if (cg == 0) { als4[(size_t)n * 4 + head] = ps; ald4[(size_t)n * 4 + head] = pd; }
    }
}

// =================== fused per-(node,head) softmax + aggregate + bias(+gelu) ===================
// one wave per (node, head); lane = output channel (phase B) / edge slot (phase A).
// NPB nodes per block (block = 64*H*NPB threads). Softmax without max-shift
// (logits are O(+-5); exp(e)/sum(exp(e)) is shift-invariant). Edge src/weight
// broadcast from lane registers via __shfl; 8 independent accumulators.
template<int H, int NPB, bool GELU>
__global__ __launch_bounds__(64 * H * NPB) void node_agg(
    const int* __restrict__ row_ptr, const int* __restrict__ col,
    const float* __restrict__ als4, const float* __restrict__ ald4,
    const float* __restrict__ htab, const float* __restrict__ bias,
    float* __restrict__ xout)
{
    const int tid = threadIdx.x;
    const int w = tid >> 6;
    const int lane = tid & 63;
    const int nl = w / H;
    const int hh = w % H;
    const int n = blockIdx.x * NPB + nl;
    const int start = row_ptr[n], end = row_ptr[n + 1];
    const int deg = end - start;
    const int dcap = deg < 64 ? deg : 64;
    const int M = H * 64;

    const float aldv = ald4[(size_t)n * 4 + hh];

    // ---- phase A: per-lane edge logit, exp, wave sum ----
    int sreg = 0;
    float myex = 0.f;
    if (lane < dcap) {
        sreg = col[start + lane];
        float t = als4[(size_t)sreg * 4 + hh] + aldv;
        t = (t >= 0.f) ? t : 0.2f * t;
        myex = expf(t);
    }
    float sum = myex;
    for (int i = start + 64 + lane; i < end; i += 64) {     // deg>64 extras (~never)
        int s = col[i];
        float t = als4[(size_t)s * 4 + hh] + aldv;
        t = (t >= 0.f) ? t : 0.2f * t;
        sum += expf(t);
    }
    #pragma unroll
    for (int off = 1; off < 64; off <<= 1)
        sum += __shfl_xor(sum, off, 64);
    const float rd = (1.0f / (float)H) / sum;
    const float wreg = myex * rd;                            // 0 for idle lanes

    // ---- phase B: 8 independent accumulators, src/weight via shfl ----
    const float* hb = htab + hh * 64 + lane;
    float av[8];
    #pragma unroll
    for (int u = 0; u < 8; ++u) av[u] = 0.f;
    for (int j = 0; j < dcap; j += 8) {
        #pragma unroll
        for (int u = 0; u < 8; ++u) {
            int   s  = __shfl(sreg, j + u, 64);              // 0 if slot idle
            float wv = __shfl(wreg, j + u, 64);              // 0 if slot idle
            av[u] = fmaf(wv, hb[(size_t)s * M], av[u]);
        }
    }
    for (int jj = 64; jj < deg; ++jj) {                      // deg>64 extras (~never)
        int s = col[start + jj];
        float t = als4[(size_t)s * 4 + hh] + aldv;
        t = (t >= 0.f) ? t : 0.2f * t;
        av[0] = fmaf(expf(t) * rd, hb[(size_t)s * M], av[0]);
    }
    float avs = ((av[0] + av[1]) + (av[2] + av[3])) + ((av[4] + av[5]) + (av[6] + av[7]));

    if (H == 1) {
        float v = avs + bias[lane];
        if (GELU) v = 0.5f * v * (1.f + erff(v * 0.70710678118654752f));
        xout[(size_t)n * 64 + lane] = v;
    } else {
        __shared__ float part[NPB][H][64];
        part[nl][hh][lane] = avs;
        __syncthreads();
        if (hh == 0) {
            float v = bias[lane];
            #pragma unroll
            for (int q = 0; q < H; ++q) v += part[nl][q][lane];
            if (GELU) v = 0.5f * v * (1.f + erff(v * 0.70710678118654752f));
            xout[(size_t)n * 64 + lane] = v;
        }
    }
}

// =================== host launch ===================

extern "C" void kernel_launch(void* const* d_in, const int* in_sizes, int n_in,
                              void* d_out, int out_size, void* d_ws, size_t ws_size,
                              hipStream_t stream) {
    const float* x0  = (const float*)d_in[0];
    const int*   ei  = (const int*)d_in[1];
    const int* srcv = ei;
    const int* dstv = ei + NEDGE;

    const float* W[3]  = { (const float*)d_in[2], (const float*)d_in[6],  (const float*)d_in[10] };
    const float* As[3] = { (const float*)d_in[3], (const float*)d_in[7],  (const float*)d_in[11] };
    const float* Ad[3] = { (const float*)d_in[4], (const float*)d_in[8],  (const float*)d_in[12] };
    const float* B[3]  = { (const float*)d_in[5], (const float*)d_in[9],  (const float*)d_in[13] };

    // workspace layout
    float* wsf   = (float*)d_ws;
    float* h     = wsf;                                  // N*192 f32
    float* als4  = h + (size_t)NODES * 192;              // N*4 (padded)
    float* ald4  = als4 + (size_t)NODES * 4;             // N*4 (padded)
    float* x1    = ald4 + (size_t)NODES * 4;             // N*64
    float* x2    = x1 + (size_t)NODES * 64;              // N*64
    int* cnt     = (int*)(x2 + (size_t)NODES * 64);      // N
    int* row_ptr = cnt + NODES;                          // N+1
    int* cursor  = row_ptr + NODES + 1;                  // N
    int* col     = cursor + NODES;                       // ETOT

    const int TB = 256;
    const int edgeBlocks = (ETOT + TB - 1) / TB;

    // ---- CSR build (self-loops included as virtual edges) ----
    hipMemsetAsync(cnt, 0, NODES * sizeof(int), stream);
    hipLaunchKernelGGL(hist_kernel, dim3(edgeBlocks), dim3(TB), 0, stream, dstv, cnt);
    hipLaunchKernelGGL(scan_csr, dim3(1), dim3(1024), 0, stream, cnt, row_ptr, cursor);
    hipLaunchKernelGGL(fill_csr, dim3(edgeBlocks), dim3(TB), 0, stream, srcv, dstv, cursor, col);

    // ---- layer 0: cin=128, H=3, mean + gelu ----
    hipLaunchKernelGGL((linear_al<128>), dim3(NODES / 128, 3), dim3(TB), 0, stream,
                       x0, W[0], As[0], Ad[0], h, als4, ald4, 3);
    hipLaunchKernelGGL((node_agg<3, 2, true>), dim3(NODES / 2), dim3(384), 0, stream,
                       row_ptr, col, als4, ald4, h, B[0], x1);

    // ---- layer 1: cin=64, H=3, mean + gelu ----
    hipLaunchKernelGGL((linear_al<64>), dim3(NODES / 128, 3), dim3(TB), 0, stream,
                       x1, W[1], As[1], Ad[1], h, als4, ald4, 3);
    hipLaunchKernelGGL((node_agg<3, 2, true>), dim3(NODES / 2), dim3(384), 0, stream,
                       row_ptr, col, als4, ald4, h, B[1], x2);

    // ---- layer 2: cin=64, H=1, concat, no activation ----
    hipLaunchKernelGGL((linear_al<64>), dim3(NODES / 128, 1), dim3(TB), 0, stream,
                       x2, W[2], As[2], Ad[2], h, als4, ald4, 1);
    hipLaunchKernelGGL((node_agg<1, 4, false>), dim3(NODES / 4), dim3(256), 0, stream,
                       row_ptr, col, als4, ald4, h, B[2], (float*)d_out);
}